// Round 1
// baseline (1047.671 us; speedup 1.0000x reference)
//
#include <hip/hip_runtime.h>
#include <math.h>

// Sizes (fixed for this problem)
#define BB   8192
#define NIN  1433
#define NH   64
#define SUBG 6
#define HID  128

__device__ __forceinline__ float allred64(float v) {
#pragma unroll
  for (int m = 1; m < 64; m <<= 1) v += __shfl_xor(v, m, 64);
  return v;
}

// ---------------- Kernel 1: GCN (both seqs) ----------------
// grid.x = 1024: [0,512) -> seq1, [512,1024) -> seq2. 16 batches (96 rows) per block.
__global__ __launch_bounds__(256) void gcn_kernel(
    const float* __restrict__ seq1, const float* __restrict__ seq2,
    const float* __restrict__ adj1, const float* __restrict__ adj2,
    const float* __restrict__ W, const float* __restrict__ bias,
    const float* __restrict__ aP,
    float* __restrict__ h1, float* __restrict__ h2)
{
  __shared__ float sA[96 * 68];
  __shared__ float sW[64 * 68];
  const int tid = threadIdx.x;
  const int sid = blockIdx.x >> 9;
  const int bb  = blockIdx.x & 511;
  const float* __restrict__ seq = sid ? seq2 : seq1;
  const float* __restrict__ adj = sid ? adj2 : adj1;
  float* __restrict__ hout = sid ? h2 : h1;
  const int b0   = bb << 4;       // first batch of this block
  const int row0 = b0 * SUBG;     // first global row (rows are contiguous: (b*6+n))
  const int rg = tid >> 4;        // 0..15 : batch within block (owns its 6 rows)
  const int cg = tid & 15;        // cols cg + 16*cc

  float acc[6][4];
#pragma unroll
  for (int i = 0; i < 6; ++i)
#pragma unroll
    for (int j = 0; j < 4; ++j) acc[i][j] = 0.f;

  for (int k0 = 0; k0 < NIN; k0 += 64) {
#pragma unroll
    for (int i = 0; i < 24; ++i) {            // 96x64 seq chunk
      int idx = i * 256 + tid;
      int r = idx >> 6, kk = idx & 63;
      int gk = k0 + kk;
      sA[r * 68 + kk] = (gk < NIN) ? seq[(row0 + r) * NIN + gk] : 0.f;
    }
#pragma unroll
    for (int i = 0; i < 16; ++i) {            // 64x64 W chunk
      int idx = i * 256 + tid;
      int c = idx >> 6, kk = idx & 63;
      int gk = k0 + kk;
      sW[c * 68 + kk] = (gk < NIN) ? W[c * NIN + gk] : 0.f;
    }
    __syncthreads();
#pragma unroll 2
    for (int kks = 0; kks < 16; ++kks) {
      float4 av[6], wv[4];
#pragma unroll
      for (int rr = 0; rr < 6; ++rr)
        av[rr] = *(const float4*)&sA[(6 * rg + rr) * 68 + 4 * kks];
#pragma unroll
      for (int cc = 0; cc < 4; ++cc)
        wv[cc] = *(const float4*)&sW[(cg + 16 * cc) * 68 + 4 * kks];
#pragma unroll
      for (int rr = 0; rr < 6; ++rr)
#pragma unroll
        for (int cc = 0; cc < 4; ++cc) {
          acc[rr][cc] = fmaf(av[rr].x, wv[cc].x, acc[rr][cc]);
          acc[rr][cc] = fmaf(av[rr].y, wv[cc].y, acc[rr][cc]);
          acc[rr][cc] = fmaf(av[rr].z, wv[cc].z, acc[rr][cc]);
          acc[rr][cc] = fmaf(av[rr].w, wv[cc].w, acc[rr][cc]);
        }
    }
    __syncthreads();
  }

  // adjacency combine + bias + prelu (thread owns all 6 rows of batch b0+rg)
  const int b = b0 + rg;
  const float a = aP[0];
  float bias4[4];
#pragma unroll
  for (int cc = 0; cc < 4; ++cc) bias4[cc] = bias[cg + 16 * cc];
  const float* __restrict__ Ab = adj + b * 36;
  float adjv[36];
#pragma unroll
  for (int m = 0; m < 36; ++m) adjv[m] = Ab[m];
#pragma unroll
  for (int n = 0; n < 6; ++n) {
#pragma unroll
    for (int cc = 0; cc < 4; ++cc) {
      float o = bias4[cc];
#pragma unroll
      for (int m = 0; m < 6; ++m) o = fmaf(adjv[n * 6 + m], acc[m][cc], o);
      o = (o >= 0.f) ? o : a * o;
      hout[(b * SUBG + n) * NH + cg + 16 * cc] = o;
    }
  }
}

// ---------------- Kernel 2: sinkhorn score + t = discW @ c ----------------
// one wave per batch; lane = feature index
__global__ __launch_bounds__(256) void sink_kernel(
    const float* __restrict__ h1, const float* __restrict__ h2,
    const float* __restrict__ resc, const float* __restrict__ discW,
    float* __restrict__ out, float* __restrict__ tws)
{
  const int b = (blockIdx.x << 2) + (threadIdx.x >> 6);
  const int lane = threadIdx.x & 63;
  const float* p1 = h1 + b * (SUBG * NH);
  const float* p2 = h2 + b * (SUBG * NH);
  float g1[5], g2[5];
#pragma unroll
  for (int i = 0; i < 4; ++i) { g1[i] = p1[i * 64 + lane]; g2[i] = p2[i * 64 + lane]; }
  g1[4] = p1[5 * 64 + lane];  g2[4] = p2[5 * 64 + lane];   // swapped row
  const float n1 = p1[4 * 64 + lane], n2 = p2[4 * 64 + lane];

  // disc "c" vector (mean of h1 rows 0..4) and t = W @ c
  {
    float cm = (g1[0] + g1[1] + g1[2] + g1[3] + n1) * 0.2f;
    float t = 0.f;
    const float4* W4 = (const float4*)discW;
#pragma unroll 4
    for (int jq = 0; jq < 16; ++jq) {
      float4 w = W4[lane * 16 + jq];
      t = fmaf(w.x, __shfl(cm, 4 * jq, 64), t);
      t = fmaf(w.y, __shfl(cm, 4 * jq + 1, 64), t);
      t = fmaf(w.z, __shfl(cm, 4 * jq + 2, 64), t);
      t = fmaf(w.w, __shfl(cm, 4 * jq + 3, 64), t);
    }
    tws[b * 64 + lane] = t;
  }

  float in1[5], in2[5];
#pragma unroll
  for (int i = 0; i < 5; ++i) {
    float s = allred64(g1[i] * g1[i]);
    in1[i] = 1.f / fmaxf(sqrtf(s), 1e-12f);
    s = allred64(g2[i] * g2[i]);
    in2[i] = 1.f / fmaxf(sqrtf(s), 1e-12f);
  }
  float cost[25], P[25];
#pragma unroll
  for (int i = 0; i < 5; ++i)
#pragma unroll
    for (int j = 0; j < 5; ++j) {
      float d = allred64(g1[i] * g2[j]);
      float cv = (1.f - d * in1[i] * in2[j]) * resc[b * 25 + i * 5 + j];
      cost[i * 5 + j] = cv;
      P[i * 5 + j] = expf(-20.f * cv);
    }
  float r[5], c[5];
  float rs = 0.f, cs = 0.f;
#pragma unroll
  for (int i = 0; i < 5; ++i) {
    float d = allred64(g1[i] * n2); d = (d <= 0.f) ? 1e-8f : d; r[i] = d; rs += d;
    d = allred64(g2[i] * n1);       d = (d <= 0.f) ? 1e-8f : d; c[i] = d; cs += d;
  }
#pragma unroll
  for (int i = 0; i < 5; ++i) { r[i] = r[i] / rs; c[i] = c[i] / cs; }

  float u[5], v[5];
#pragma unroll
  for (int i = 0; i < 5; ++i) u[i] = 0.2f;
#pragma unroll
  for (int it = 0; it < 5; ++it) {
#pragma unroll
    for (int i = 0; i < 5; ++i) {
      float pv = 0.f;
#pragma unroll
      for (int j = 0; j < 5; ++j) pv = fmaf(P[i * 5 + j], u[j], pv);
      v[i] = r[i] / pv;
    }
#pragma unroll
    for (int i = 0; i < 5; ++i) {
      float pu = 0.f;
#pragma unroll
      for (int j = 0; j < 5; ++j) pu = fmaf(P[j * 5 + i], v[j], pu);
      u[i] = c[i] / pu;
    }
  }
  float S = 0.f;
#pragma unroll
  for (int i = 0; i < 5; ++i)
#pragma unroll
    for (int j = 0; j < 5; ++j)
      S += v[i] * P[i * 5 + j] * u[j] * (1.f - cost[i * 5 + j]);
  if (lane == 0) out[(size_t)b * 1436] = expf(S * 2.5f) * 2.f;
}

// ---------------- Kernel 3: decoder (3 fused dense layers) ----------------
// 16 batches per block; 512 blocks
__global__ __launch_bounds__(256) void dec_kernel(
    const float* __restrict__ h1,
    const float* __restrict__ W1, const float* __restrict__ b1, const float* __restrict__ a1P,
    const float* __restrict__ W2, const float* __restrict__ b2, const float* __restrict__ a2P,
    const float* __restrict__ W3, const float* __restrict__ b3, const float* __restrict__ a3P,
    float* __restrict__ out)
{
  __shared__ float sX[16 * 68];
  __shared__ float sWt[128 * 68];
  __shared__ float sX2[16 * 132];
  const int tid = threadIdx.x;
  const int b0 = blockIdx.x << 4;
  const int rg = tid >> 4;   // row (batch) 0..15
  const int cg = tid & 15;   // cols cg + 16*cc

  float acc[8];
  // ---- layer 1: 256 -> 128 ----
#pragma unroll
  for (int cc = 0; cc < 8; ++cc) acc[cc] = 0.f;
  for (int kc = 0; kc < 4; ++kc) {
    const int k0 = kc * 64;
#pragma unroll
    for (int i = 0; i < 4; ++i) {
      int idx = i * 256 + tid; int r = idx >> 6, kk = idx & 63;
      sX[r * 68 + kk] = h1[(b0 + r) * (SUBG * NH) + k0 + kk];  // rows 0..3 = first 256 floats
    }
#pragma unroll
    for (int i = 0; i < 32; ++i) {
      int idx = i * 256 + tid; int o = idx >> 6, kk = idx & 63;
      sWt[o * 68 + kk] = W1[o * 256 + k0 + kk];
    }
    __syncthreads();
#pragma unroll 4
    for (int kks = 0; kks < 16; ++kks) {
      float4 a = *(const float4*)&sX[rg * 68 + 4 * kks];
#pragma unroll
      for (int cc = 0; cc < 8; ++cc) {
        float4 w = *(const float4*)&sWt[(cg + 16 * cc) * 68 + 4 * kks];
        acc[cc] = fmaf(a.x, w.x, acc[cc]);
        acc[cc] = fmaf(a.y, w.y, acc[cc]);
        acc[cc] = fmaf(a.z, w.z, acc[cc]);
        acc[cc] = fmaf(a.w, w.w, acc[cc]);
      }
    }
    __syncthreads();
  }
  {
    const float a1 = a1P[0];
#pragma unroll
    for (int cc = 0; cc < 8; ++cc) {
      int col = cg + 16 * cc;
      float o = acc[cc] + b1[col];
      o = (o >= 0.f) ? o : a1 * o;
      sX2[rg * 132 + col] = o;
    }
  }
  __syncthreads();

  // ---- layer 2: 128 -> 128 ----
#pragma unroll
  for (int cc = 0; cc < 8; ++cc) acc[cc] = 0.f;
  for (int kc = 0; kc < 2; ++kc) {
    const int k0 = kc * 64;
#pragma unroll
    for (int i = 0; i < 32; ++i) {
      int idx = i * 256 + tid; int o = idx >> 6, kk = idx & 63;
      sWt[o * 68 + kk] = W2[o * 128 + k0 + kk];
    }
    __syncthreads();
#pragma unroll 4
    for (int kks = 0; kks < 16; ++kks) {
      float4 a = *(const float4*)&sX2[rg * 132 + k0 + 4 * kks];
#pragma unroll
      for (int cc = 0; cc < 8; ++cc) {
        float4 w = *(const float4*)&sWt[(cg + 16 * cc) * 68 + 4 * kks];
        acc[cc] = fmaf(a.x, w.x, acc[cc]);
        acc[cc] = fmaf(a.y, w.y, acc[cc]);
        acc[cc] = fmaf(a.z, w.z, acc[cc]);
        acc[cc] = fmaf(a.w, w.w, acc[cc]);
      }
    }
    __syncthreads();
  }
  {
    const float a2 = a2P[0];
    float x3v[8];
#pragma unroll
    for (int cc = 0; cc < 8; ++cc) {
      int col = cg + 16 * cc;
      float o = acc[cc] + b2[col];
      x3v[cc] = (o >= 0.f) ? o : a2 * o;
    }
    // all reads of sX2 finished (loop above ends with syncthreads)
#pragma unroll
    for (int cc = 0; cc < 8; ++cc) sX2[rg * 132 + cg + 16 * cc] = x3v[cc];
  }
  __syncthreads();

  // ---- layer 3: 128 -> 1433 ----
  const float a3 = a3P[0];
  for (int oc = 0; oc < 12; ++oc) {
    const int o0 = oc * 128;
#pragma unroll
    for (int cc = 0; cc < 8; ++cc) acc[cc] = 0.f;
    for (int kc = 0; kc < 2; ++kc) {
      const int k0 = kc * 64;
#pragma unroll
      for (int i = 0; i < 32; ++i) {
        int idx = i * 256 + tid; int orow = idx >> 6, kk = idx & 63;
        int o = o0 + orow;
        sWt[orow * 68 + kk] = (o < NIN) ? W3[o * 128 + k0 + kk] : 0.f;
      }
      __syncthreads();
#pragma unroll 4
      for (int kks = 0; kks < 16; ++kks) {
        float4 a = *(const float4*)&sX2[rg * 132 + k0 + 4 * kks];
#pragma unroll
        for (int cc = 0; cc < 8; ++cc) {
          float4 w = *(const float4*)&sWt[(cg + 16 * cc) * 68 + 4 * kks];
          acc[cc] = fmaf(a.x, w.x, acc[cc]);
          acc[cc] = fmaf(a.y, w.y, acc[cc]);
          acc[cc] = fmaf(a.z, w.z, acc[cc]);
          acc[cc] = fmaf(a.w, w.w, acc[cc]);
        }
      }
      __syncthreads();
    }
#pragma unroll
    for (int cc = 0; cc < 8; ++cc) {
      int col = cg + 16 * cc;
      int o = o0 + col;
      if (o < NIN) {
        float vv = acc[cc] + b3[o];
        vv = (vv >= 0.f) ? vv : a3 * vv;
        out[(size_t)(b0 + rg) * 1436 + 1 + o] = vv;
      }
    }
  }
}

// ---------------- Kernel 4: discriminator logits ----------------
__global__ __launch_bounds__(256) void disc_kernel(
    const float* __restrict__ h1, const float* __restrict__ tws,
    const float* __restrict__ dbP, float* __restrict__ out)
{
  const int b = (blockIdx.x << 2) + (threadIdx.x >> 6);
  const int lane = threadIdx.x & 63;
  float hp = h1[(b * SUBG + 5) * NH + lane];
  float t0 = tws[b * 64 + lane];
  int bp = (b == 0) ? (BB - 2) : (b - 1);
  float tp = tws[bp * 64 + lane];
  float s1 = allred64(hp * t0);
  float s2 = allred64(hp * tp);
  if (lane == 0) {
    float db = dbP[0];
    out[(size_t)b * 1436 + 1434] = s1 + db;
    out[(size_t)b * 1436 + 1435] = s2 + db;
  }
}

extern "C" void kernel_launch(void* const* d_in, const int* in_sizes, int n_in,
                              void* d_out, int out_size, void* d_ws, size_t ws_size,
                              hipStream_t stream) {
  (void)in_sizes; (void)n_in; (void)out_size; (void)ws_size;
  const float* seq1  = (const float*)d_in[0];
  const float* seq2  = (const float*)d_in[1];
  const float* adj1  = (const float*)d_in[2];
  const float* adj2  = (const float*)d_in[3];
  const float* resc  = (const float*)d_in[4];
  const float* gcnW  = (const float*)d_in[5];
  const float* gcnB  = (const float*)d_in[6];
  const float* gcnA  = (const float*)d_in[7];
  const float* W1    = (const float*)d_in[8];
  const float* b1    = (const float*)d_in[9];
  const float* a1    = (const float*)d_in[10];
  const float* W2    = (const float*)d_in[11];
  const float* b2    = (const float*)d_in[12];
  const float* a2    = (const float*)d_in[13];
  const float* W3    = (const float*)d_in[14];
  const float* b3    = (const float*)d_in[15];
  const float* a3    = (const float*)d_in[16];
  const float* discW = (const float*)d_in[17];
  const float* discB = (const float*)d_in[18];

  float* h1  = (float*)d_ws;
  float* h2  = h1 + (size_t)BB * SUBG * NH;
  float* tws = h2 + (size_t)BB * SUBG * NH;
  float* out = (float*)d_out;

  gcn_kernel<<<1024, 256, 0, stream>>>(seq1, seq2, adj1, adj2, gcnW, gcnB, gcnA, h1, h2);
  sink_kernel<<<2048, 256, 0, stream>>>(h1, h2, resc, discW, out, tws);
  dec_kernel<<<512, 256, 0, stream>>>(h1, W1, b1, a1, W2, b2, a2, W3, b3, a3, out);
  disc_kernel<<<2048, 256, 0, stream>>>(h1, tws, discB, out);
}

// Round 2
// 377.610 us; speedup vs baseline: 2.7745x; 2.7745x over previous
//
#include <hip/hip_runtime.h>
#include <math.h>

#define BB   8192
#define NIN  1433
#define NH   64
#define SUBG 6
#define HID  128

#define KC_G 45      // ceil(1433/32) k-chunks for GCN
#define KPAD 40      // padded k-stride per chunk (80B rows: 16B-aligned, 2-way-max LDS banks)

typedef __attribute__((ext_vector_type(8))) short bf16x8;
typedef __attribute__((ext_vector_type(4))) float f32x4;

__device__ __forceinline__ short f2bf(float x) {
  unsigned u = __float_as_uint(x);
  unsigned r = (u + 0x7fffu + ((u >> 16) & 1u)) >> 16;   // RNE
  return (short)r;
}
__device__ __forceinline__ float bf2f(short s) {
  return __uint_as_float(((unsigned)(unsigned short)s) << 16);
}
__device__ __forceinline__ float allred64(float v) {
#pragma unroll
  for (int m = 1; m < 64; m <<= 1) v += __shfl_xor(v, m, 64);
  return v;
}

// ---------------- prep: split W into packed bf16 hi/lo fragment layout ----------------
// B[k][o] = src[o][k]; layout dst[((c*Opad + o)*KPAD + kk)] with k = c*32+kk, kk<32.
__global__ void pack_kernel(const float* __restrict__ src, short* __restrict__ hi,
                            short* __restrict__ lo, int Oreal, int Opad, int Kreal, int nchunk) {
  int idx = blockIdx.x * 256 + threadIdx.x;
  int total = nchunk * Opad * 32;
  if (idx >= total) return;
  int kk = idx & 31;
  int o  = (idx >> 5) % Opad;
  int c  = idx / (Opad * 32);
  int k  = c * 32 + kk;
  float v = (o < Oreal && k < Kreal) ? src[(size_t)o * Kreal + k] : 0.f;
  short h = f2bf(v);
  short l = f2bf(v - bf2f(h));
  size_t off = ((size_t)(c * Opad + o)) * KPAD + kk;
  hi[off] = h; lo[off] = l;
}

// ---------------- Kernel 1: GCN via split-bf16 MFMA ----------------
// 384 threads (6 waves). Each wave: 16 rows x 64 cols, K=1433.
// Block: 96 rows = 16 batches. grid 1024 ([0,512)=seq1).
__global__ __launch_bounds__(384) void gcn_mfma(
    const float* __restrict__ seq1, const float* __restrict__ seq2,
    const float* __restrict__ adj1, const float* __restrict__ adj2,
    const short* __restrict__ Gh, const short* __restrict__ Gl,
    const float* __restrict__ bias, const float* __restrict__ aP,
    float* __restrict__ h1, float* __restrict__ h2)
{
  __shared__ short sB[2][64 * KPAD];   // [hi/lo][o*KPAD+kk], 5120B each
  __shared__ float fts[96][68];
  const int tid = threadIdx.x;
  const int sid = blockIdx.x >> 9;
  const int bb  = blockIdx.x & 511;
  const float* __restrict__ seq = sid ? seq2 : seq1;
  const float* __restrict__ adj = sid ? adj2 : adj1;
  float* __restrict__ hout = sid ? h2 : h1;
  const int b0 = bb << 4;
  const int row0 = b0 * SUBG;
  const int w = tid >> 6, lane = tid & 63;
  const int l15 = lane & 15, lg = lane >> 4;

  f32x4 acc[4];
#pragma unroll
  for (int i = 0; i < 4; ++i) acc[i] = (f32x4){0.f, 0.f, 0.f, 0.f};

  const float* aptr = seq + (size_t)(row0 + w * 16 + l15) * NIN;

  // staging regs: 640 16B pieces per chunk (hi 320 + lo 320), 2 rounds of 384 threads
  bf16x8 stg0, stg1;
  {
    int i0 = tid, i1 = 384 + tid;
    if (i0 < 640) stg0 = *(const bf16x8*)((i0 < 320 ? Gh : Gl) + (i0 % 320) * 8);
    if (i1 < 640) stg1 = *(const bf16x8*)((i1 < 320 ? Gh : Gl) + (i1 % 320) * 8);
  }

  for (int c = 0; c < KC_G; ++c) {
    __syncthreads();                       // previous compute done reading sB
    {
      int i0 = tid, i1 = 384 + tid;
      if (i0 < 640) *(bf16x8*)((i0 < 320 ? sB[0] : sB[1]) + (i0 % 320) * 8) = stg0;
      if (i1 < 640) *(bf16x8*)((i1 < 320 ? sB[0] : sB[1]) + (i1 % 320) * 8) = stg1;
    }
    __syncthreads();
    if (c + 1 < KC_G) {                    // issue next-chunk loads early (overlap compute)
      int i0 = tid, i1 = 384 + tid;
      size_t base = (size_t)(c + 1) * 2560;
      if (i0 < 640) stg0 = *(const bf16x8*)((i0 < 320 ? Gh : Gl) + base + (i0 % 320) * 8);
      if (i1 < 640) stg1 = *(const bf16x8*)((i1 < 320 ? Gh : Gl) + base + (i1 % 320) * 8);
    }
    // A: 8 consecutive f32 at k0, convert to hi/lo bf16
    float av[8];
    int k0 = c * 32 + lg * 8;
    if (c < KC_G - 1) {
      float4 p, q;
      __builtin_memcpy(&p, aptr + k0, 16);       // rows stride 1433: only 4B-aligned
      __builtin_memcpy(&q, aptr + k0 + 4, 16);
      av[0] = p.x; av[1] = p.y; av[2] = p.z; av[3] = p.w;
      av[4] = q.x; av[5] = q.y; av[6] = q.z; av[7] = q.w;
    } else {
#pragma unroll
      for (int j = 0; j < 8; ++j) { int k = k0 + j; av[j] = (k < NIN) ? aptr[k] : 0.f; }
    }
    bf16x8 Ah, Al;
#pragma unroll
    for (int j = 0; j < 8; ++j) {
      short h = f2bf(av[j]);
      Ah[j] = h;
      Al[j] = f2bf(av[j] - bf2f(h));
    }
#pragma unroll
    for (int nf = 0; nf < 4; ++nf) {
      const int boff = (nf * 16 + l15) * KPAD + lg * 8;
      bf16x8 Bh = *(const bf16x8*)&sB[0][boff];
      bf16x8 Bl = *(const bf16x8*)&sB[1][boff];
      acc[nf] = __builtin_amdgcn_mfma_f32_16x16x32_bf16(Ah, Bh, acc[nf], 0, 0, 0);
      acc[nf] = __builtin_amdgcn_mfma_f32_16x16x32_bf16(Al, Bh, acc[nf], 0, 0, 0);
      acc[nf] = __builtin_amdgcn_mfma_f32_16x16x32_bf16(Ah, Bl, acc[nf], 0, 0, 0);
    }
  }
  // C frags -> fts LDS (D: row=(l>>4)*4+j, col=l&15)
#pragma unroll
  for (int nf = 0; nf < 4; ++nf)
#pragma unroll
    for (int j = 0; j < 4; ++j)
      fts[w * 16 + lg * 4 + j][nf * 16 + l15] = acc[nf][j];
  __syncthreads();

  // adjacency combine + bias + prelu. thread: col = tid&63, n = tid>>6 (0..5)
  const float a = aP[0];
  const int ccol = tid & 63, nn = tid >> 6;
  const float bv = bias[ccol];
  for (int b = 0; b < 16; ++b) {
    const float* Ab = adj + (size_t)(b0 + b) * 36 + nn * 6;
    float o = bv;
#pragma unroll
    for (int m = 0; m < 6; ++m) o = fmaf(Ab[m], fts[b * 6 + m][ccol], o);
    o = (o >= 0.f) ? o : a * o;
    hout[((size_t)(b0 + b) * SUBG + nn) * NH + ccol] = o;
  }
}

// ---------------- Kernel 2: sinkhorn score + t = discW @ c ----------------
__global__ __launch_bounds__(256) void sink_kernel(
    const float* __restrict__ h1, const float* __restrict__ h2,
    const float* __restrict__ resc, const float* __restrict__ discW,
    float* __restrict__ out, float* __restrict__ tws)
{
  const int b = (blockIdx.x << 2) + (threadIdx.x >> 6);
  const int lane = threadIdx.x & 63;
  const float* p1 = h1 + (size_t)b * (SUBG * NH);
  const float* p2 = h2 + (size_t)b * (SUBG * NH);
  float g1[5], g2[5];
#pragma unroll
  for (int i = 0; i < 4; ++i) { g1[i] = p1[i * 64 + lane]; g2[i] = p2[i * 64 + lane]; }
  g1[4] = p1[5 * 64 + lane];  g2[4] = p2[5 * 64 + lane];
  const float n1 = p1[4 * 64 + lane], n2 = p2[4 * 64 + lane];

  {
    float cm = (g1[0] + g1[1] + g1[2] + g1[3] + n1) * 0.2f;
    float t = 0.f;
    const float4* W4 = (const float4*)discW;
#pragma unroll 4
    for (int jq = 0; jq < 16; ++jq) {
      float4 w = W4[lane * 16 + jq];
      t = fmaf(w.x, __shfl(cm, 4 * jq, 64), t);
      t = fmaf(w.y, __shfl(cm, 4 * jq + 1, 64), t);
      t = fmaf(w.z, __shfl(cm, 4 * jq + 2, 64), t);
      t = fmaf(w.w, __shfl(cm, 4 * jq + 3, 64), t);
    }
    tws[(size_t)b * 64 + lane] = t;
  }

  float in1[5], in2[5];
#pragma unroll
  for (int i = 0; i < 5; ++i) {
    float s = allred64(g1[i] * g1[i]);
    in1[i] = 1.f / fmaxf(sqrtf(s), 1e-12f);
    s = allred64(g2[i] * g2[i]);
    in2[i] = 1.f / fmaxf(sqrtf(s), 1e-12f);
  }
  float cost[25], P[25];
#pragma unroll
  for (int i = 0; i < 5; ++i)
#pragma unroll
    for (int j = 0; j < 5; ++j) {
      float d = allred64(g1[i] * g2[j]);
      float cv = (1.f - d * in1[i] * in2[j]) * resc[(size_t)b * 25 + i * 5 + j];
      cost[i * 5 + j] = cv;
      P[i * 5 + j] = expf(-20.f * cv);
    }
  float r[5], c[5];
  float rs = 0.f, cs = 0.f;
#pragma unroll
  for (int i = 0; i < 5; ++i) {
    float d = allred64(g1[i] * n2); d = (d <= 0.f) ? 1e-8f : d; r[i] = d; rs += d;
    d = allred64(g2[i] * n1);       d = (d <= 0.f) ? 1e-8f : d; c[i] = d; cs += d;
  }
#pragma unroll
  for (int i = 0; i < 5; ++i) { r[i] = r[i] / rs; c[i] = c[i] / cs; }

  float u[5], v[5];
#pragma unroll
  for (int i = 0; i < 5; ++i) u[i] = 0.2f;
#pragma unroll
  for (int it = 0; it < 5; ++it) {
#pragma unroll
    for (int i = 0; i < 5; ++i) {
      float pv = 0.f;
#pragma unroll
      for (int j = 0; j < 5; ++j) pv = fmaf(P[i * 5 + j], u[j], pv);
      v[i] = r[i] / pv;
    }
#pragma unroll
    for (int i = 0; i < 5; ++i) {
      float pu = 0.f;
#pragma unroll
      for (int j = 0; j < 5; ++j) pu = fmaf(P[j * 5 + i], v[j], pu);
      u[i] = c[i] / pu;
    }
  }
  float S = 0.f;
#pragma unroll
  for (int i = 0; i < 5; ++i)
#pragma unroll
    for (int j = 0; j < 5; ++j)
      S += v[i] * P[i * 5 + j] * u[j] * (1.f - cost[i * 5 + j]);
  if (lane == 0) out[(size_t)b * 1436] = expf(S * 2.5f) * 2.f;
}

// ---------------- Kernel 3a: decoder layers 1+2 (MFMA) -> x3 ----------------
// 1 wave per block, 16 rows; grid 512
__global__ __launch_bounds__(64) void dec12_mfma(
    const float* __restrict__ h1,
    const short* __restrict__ B1h, const short* __restrict__ B1l,
    const float* __restrict__ b1, const float* __restrict__ a1P,
    const short* __restrict__ B2h, const short* __restrict__ B2l,
    const float* __restrict__ b2, const float* __restrict__ a2P,
    float* __restrict__ x3)
{
  __shared__ float xT[16][132];
  const int lane = threadIdx.x;
  const int l15 = lane & 15, lg = lane >> 4;
  const int r0 = blockIdx.x * 16;

  f32x4 acc[8];
#pragma unroll
  for (int i = 0; i < 8; ++i) acc[i] = (f32x4){0.f, 0.f, 0.f, 0.f};

  // ---- layer 1: K=256 (x = first 256 floats of each batch's h1), O=128 ----
#pragma unroll
  for (int c = 0; c < 8; ++c) {
    const float* ap = h1 + (size_t)(r0 + l15) * 384 + c * 32 + lg * 8;
    float4 p = *(const float4*)ap;
    float4 q = *(const float4*)(ap + 4);
    float av[8] = {p.x, p.y, p.z, p.w, q.x, q.y, q.z, q.w};
    bf16x8 Ah, Al;
#pragma unroll
    for (int j = 0; j < 8; ++j) { short h = f2bf(av[j]); Ah[j] = h; Al[j] = f2bf(av[j] - bf2f(h)); }
#pragma unroll
    for (int nf = 0; nf < 8; ++nf) {
      size_t off = ((size_t)(c * 128 + nf * 16 + l15)) * KPAD + lg * 8;
      bf16x8 Bh = *(const bf16x8*)(B1h + off);
      bf16x8 Bl = *(const bf16x8*)(B1l + off);
      acc[nf] = __builtin_amdgcn_mfma_f32_16x16x32_bf16(Ah, Bh, acc[nf], 0, 0, 0);
      acc[nf] = __builtin_amdgcn_mfma_f32_16x16x32_bf16(Al, Bh, acc[nf], 0, 0, 0);
      acc[nf] = __builtin_amdgcn_mfma_f32_16x16x32_bf16(Ah, Bl, acc[nf], 0, 0, 0);
    }
  }
  {
    const float a1 = a1P[0];
#pragma unroll
    for (int nf = 0; nf < 8; ++nf) {
      int o = nf * 16 + l15;
      float bv = b1[o];
#pragma unroll
      for (int j = 0; j < 4; ++j) {
        float v = acc[nf][j] + bv;
        xT[lg * 4 + j][o] = (v >= 0.f) ? v : a1 * v;
      }
    }
  }
  __syncthreads();

  // ---- layer 2: K=128, O=128 ----
#pragma unroll
  for (int i = 0; i < 8; ++i) acc[i] = (f32x4){0.f, 0.f, 0.f, 0.f};
#pragma unroll
  for (int c = 0; c < 4; ++c) {
    const float* ap = &xT[l15][c * 32 + lg * 8];
    float4 p = *(const float4*)ap;
    float4 q = *(const float4*)(ap + 4);
    float av[8] = {p.x, p.y, p.z, p.w, q.x, q.y, q.z, q.w};
    bf16x8 Ah, Al;
#pragma unroll
    for (int j = 0; j < 8; ++j) { short h = f2bf(av[j]); Ah[j] = h; Al[j] = f2bf(av[j] - bf2f(h)); }
#pragma unroll
    for (int nf = 0; nf < 8; ++nf) {
      size_t off = ((size_t)(c * 128 + nf * 16 + l15)) * KPAD + lg * 8;
      bf16x8 Bh = *(const bf16x8*)(B2h + off);
      bf16x8 Bl = *(const bf16x8*)(B2l + off);
      acc[nf] = __builtin_amdgcn_mfma_f32_16x16x32_bf16(Ah, Bh, acc[nf], 0, 0, 0);
      acc[nf] = __builtin_amdgcn_mfma_f32_16x16x32_bf16(Al, Bh, acc[nf], 0, 0, 0);
      acc[nf] = __builtin_amdgcn_mfma_f32_16x16x32_bf16(Ah, Bl, acc[nf], 0, 0, 0);
    }
  }
  {
    const float a2 = a2P[0];
#pragma unroll
    for (int nf = 0; nf < 8; ++nf) {
      int o = nf * 16 + l15;
      float bv = b2[o];
#pragma unroll
      for (int j = 0; j < 4; ++j) {
        float v = acc[nf][j] + bv;
        v = (v >= 0.f) ? v : a2 * v;
        x3[(size_t)(r0 + lg * 4 + j) * 128 + o] = v;
      }
    }
  }
}

// ---------------- Kernel 3b: decoder layer 3 (MFMA, nf-split) ----------------
// 1 wave per block; grid = 512 rowblocks x 6 nf-groups
__global__ __launch_bounds__(64) void dec3_mfma(
    const float* __restrict__ x3,
    const short* __restrict__ B3h, const short* __restrict__ B3l,
    const float* __restrict__ b3, const float* __restrict__ a3P,
    float* __restrict__ out)
{
  const int lane = threadIdx.x;
  const int l15 = lane & 15, lg = lane >> 4;
  const int rowblk = blockIdx.x & 511;
  const int nfg = blockIdx.x >> 9;     // 0..5, 15 nf each (90 total)
  const int r0 = rowblk * 16;

  bf16x8 A3h[4], A3l[4];
#pragma unroll
  for (int c = 0; c < 4; ++c) {
    const float* ap = x3 + (size_t)(r0 + l15) * 128 + c * 32 + lg * 8;
    float4 p = *(const float4*)ap;
    float4 q = *(const float4*)(ap + 4);
    float av[8] = {p.x, p.y, p.z, p.w, q.x, q.y, q.z, q.w};
#pragma unroll
    for (int j = 0; j < 8; ++j) {
      short h = f2bf(av[j]); A3h[c][j] = h; A3l[c][j] = f2bf(av[j] - bf2f(h));
    }
  }
  const float a3 = a3P[0];
  for (int t = 0; t < 15; ++t) {
    const int nf = nfg * 15 + t;
    f32x4 acc = (f32x4){0.f, 0.f, 0.f, 0.f};
#pragma unroll
    for (int c = 0; c < 4; ++c) {
      size_t off = ((size_t)(c * 1440 + nf * 16 + l15)) * KPAD + lg * 8;
      bf16x8 Bh = *(const bf16x8*)(B3h + off);
      bf16x8 Bl = *(const bf16x8*)(B3l + off);
      acc = __builtin_amdgcn_mfma_f32_16x16x32_bf16(A3h[c], Bh, acc, 0, 0, 0);
      acc = __builtin_amdgcn_mfma_f32_16x16x32_bf16(A3l[c], Bh, acc, 0, 0, 0);
      acc = __builtin_amdgcn_mfma_f32_16x16x32_bf16(A3h[c], Bl, acc, 0, 0, 0);
    }
    const int o = nf * 16 + l15;
    if (o < NIN) {
      float bv = b3[o];
#pragma unroll
      for (int j = 0; j < 4; ++j) {
        float v = acc[j] + bv;
        v = (v >= 0.f) ? v : a3 * v;
        out[(size_t)(r0 + lg * 4 + j) * 1436 + 1 + o] = v;
      }
    }
  }
}

// ---------------- Kernel 4: discriminator logits ----------------
__global__ __launch_bounds__(256) void disc_kernel(
    const float* __restrict__ h1, const float* __restrict__ tws,
    const float* __restrict__ dbP, float* __restrict__ out)
{
  const int b = (blockIdx.x << 2) + (threadIdx.x >> 6);
  const int lane = threadIdx.x & 63;
  float hp = h1[((size_t)b * SUBG + 5) * NH + lane];
  float t0 = tws[(size_t)b * 64 + lane];
  int bp = (b == 0) ? (BB - 2) : (b - 1);
  float tp = tws[(size_t)bp * 64 + lane];
  float s1 = allred64(hp * t0);
  float s2 = allred64(hp * tp);
  if (lane == 0) {
    float db = dbP[0];
    out[(size_t)b * 1436 + 1434] = s1 + db;
    out[(size_t)b * 1436 + 1435] = s2 + db;
  }
}

extern "C" void kernel_launch(void* const* d_in, const int* in_sizes, int n_in,
                              void* d_out, int out_size, void* d_ws, size_t ws_size,
                              hipStream_t stream) {
  (void)in_sizes; (void)n_in; (void)out_size; (void)ws_size;
  const float* seq1  = (const float*)d_in[0];
  const float* seq2  = (const float*)d_in[1];
  const float* adj1  = (const float*)d_in[2];
  const float* adj2  = (const float*)d_in[3];
  const float* resc  = (const float*)d_in[4];
  const float* gcnW  = (const float*)d_in[5];
  const float* gcnB  = (const float*)d_in[6];
  const float* gcnA  = (const float*)d_in[7];
  const float* W1    = (const float*)d_in[8];
  const float* b1    = (const float*)d_in[9];
  const float* a1    = (const float*)d_in[10];
  const float* W2    = (const float*)d_in[11];
  const float* b2    = (const float*)d_in[12];
  const float* a2    = (const float*)d_in[13];
  const float* W3    = (const float*)d_in[14];
  const float* b3    = (const float*)d_in[15];
  const float* a3    = (const float*)d_in[16];
  const float* discW = (const float*)d_in[17];
  const float* discB = (const float*)d_in[18];

  float* h1  = (float*)d_ws;                   // 8192*384
  float* h2  = h1 + (size_t)BB * SUBG * NH;    // 8192*384
  float* tws = h2 + (size_t)BB * SUBG * NH;    // 8192*64
  float* x3  = tws + (size_t)BB * 64;          // 8192*128
  short* Gh  = (short*)(x3 + (size_t)BB * 128);
  short* Gl  = Gh  + 45 * 64 * KPAD;
  short* B1h = Gl  + 45 * 64 * KPAD;
  short* B1l = B1h + 8 * 128 * KPAD;
  short* B2h = B1l + 8 * 128 * KPAD;
  short* B2l = B2h + 4 * 128 * KPAD;
  short* B3h = B2l + 4 * 128 * KPAD;
  short* B3l = B3h + 4 * 1440 * KPAD;
  float* out = (float*)d_out;

  pack_kernel<<<(45 * 64 * 32 + 255) / 256, 256, 0, stream>>>(gcnW, Gh, Gl, 64, 64, 1433, 45);
  pack_kernel<<<(8 * 128 * 32 + 255) / 256, 256, 0, stream>>>(W1, B1h, B1l, 128, 128, 256, 8);
  pack_kernel<<<(4 * 128 * 32 + 255) / 256, 256, 0, stream>>>(W2, B2h, B2l, 128, 128, 128, 4);
  pack_kernel<<<(4 * 1440 * 32 + 255) / 256, 256, 0, stream>>>(W3, B3h, B3l, 1433, 1440, 128, 4);

  gcn_mfma<<<1024, 384, 0, stream>>>(seq1, seq2, adj1, adj2, Gh, Gl, gcnB, gcnA, h1, h2);
  sink_kernel<<<2048, 256, 0, stream>>>(h1, h2, resc, discW, out, tws);
  dec12_mfma<<<512, 64, 0, stream>>>(h1, B1h, B1l, b1, a1, B2h, B2l, b2, a2, x3);
  dec3_mfma<<<3072, 64, 0, stream>>>(x3, B3h, B3l, b3, a3, out);
  disc_kernel<<<2048, 256, 0, stream>>>(h1, tws, discB, out);
}